// Round 6
// baseline (874.840 us; speedup 1.0000x reference)
//
#include <hip/hip_runtime.h>
#include <hip/hip_bf16.h>

#define NEG_FILL -1.0e9f

using bf16x8 = __attribute__((ext_vector_type(8))) short;
using f32x4  = __attribute__((ext_vector_type(4))) float;   // native clang vector

// round-to-nearest-even fp32 -> bf16 (no NaNs in this data)
static __device__ __forceinline__ short f2bf(float f) {
    union { float f; unsigned u; } a; a.f = f;
    unsigned r = a.u + 0x7FFFu + ((a.u >> 16) & 1u);
    return (short)(r >> 16);
}

// pack 8 floats -> bf16x8 via packed cvt (v_cvt_pk_bf16_f32)
static __device__ __forceinline__ bf16x8 pack8(float4 a, float4 b) {
    union { __hip_bfloat162 h[4]; bf16x8 v; } u;
    u.h[0] = __float22bfloat162_rn({a.x, a.y});
    u.h[1] = __float22bfloat162_rn({a.z, a.w});
    u.h[2] = __float22bfloat162_rn({b.x, b.y});
    u.h[3] = __float22bfloat162_rn({b.z, b.w});
    return u.v;
}

// ws layout:
// [0, 32768)        WT  bf16 [128][128]   WT[n][k] = (W1@W2)[k][n]
// [32768, 33280)    beff f32 [128]        b1@W2 + b2
// (pool buffer eliminated -- max-pool is now block-local)

__global__ __launch_bounds__(256) void k_prep(
    const float* __restrict__ W1, const float* __restrict__ b1,
    const float* __restrict__ W2, const float* __restrict__ b2,
    short* __restrict__ WT, float* __restrict__ beff)
{
    int blk = blockIdx.x, tid = threadIdx.x;
    if (blk < 64) {                       // Weff^T: 64 blocks * 256 = 16384 entries
        int e = blk * 256 + tid;          // e = n*128 + k
        int n = e >> 7, k = e & 127;
        float s = 0.f;
        #pragma unroll 8
        for (int h = 0; h < 64; ++h) s = fmaf(W1[k * 64 + h], W2[h * 128 + n], s);
        WT[e] = f2bf(s);
    } else if (tid < 128) {               // beff
        float s = b2[tid];
        for (int h = 0; h < 64; ++h) s = fmaf(b1[h], W2[h * 128 + tid], s);
        beff[tid] = s;
    }
}

// Single fused kernel: ONE BLOCK = ONE BATCH (256 blocks x 1024 thr / 16 waves).
// Rationale (R0-R5 evidence): cross-block reduction on gfx950 is expensive in
// every form (fence handshake catastrophically so, R2), and the 3-dispatch
// chain left ~150us of slack (barrier drains at 4096 block starts, 524K
// device-scope atomics, full serialization before k_bcast, second HBM ramp).
// With the batch's 2048 rows in one block, the max-pool is block-local:
// per-column max rides in registers across 8 row-iterations, one LDS reduce
// at the end, then the block streams its own broadcast half. k_bcast, the
// pool buffer, and all global atomics are gone. Byte traffic = the mandatory
// 810 MB. Per-wave MFMA/LN code identical to the verified R3/R5 kernels.
__global__ __launch_bounds__(1024) void k_main(
    const float* __restrict__ X, const int* __restrict__ mask,
    const short* __restrict__ WT, const float* __restrict__ beff,
    const float* __restrict__ gamma, const float* __restrict__ beta,
    float* __restrict__ out)
{
    __shared__ short Ws[128][136];   // +8 shorts pad
    __shared__ __align__(16) int pool_s[128];

    const int tid  = threadIdx.x;
    const int bidx = blockIdx.x;                 // one block = one batch
    const size_t base_row = (size_t)bidx * 2048;

    if (tid < 128) pool_s[tid] = __float_as_int(NEG_FILL);

    // stage Weff^T (bf16) into LDS: 2048 x 16B over 1024 threads
    #pragma unroll
    for (int i = 0; i < 2; ++i) {
        int g = tid + i * 1024;            // short8 id
        int n = g >> 4, koff = (g & 15) * 8;
        *(bf16x8*)&Ws[n][koff] = *(const bf16x8*)(WT + g * 8);
    }

    const int wave = tid >> 6, lane = tid & 63;
    const int c = lane & 15, q = lane >> 4;

    // per-lane column params (col n = t*16 + c); L1/L2-hot
    float be[8], ga[8], bt[8];
    #pragma unroll
    for (int t = 0; t < 8; ++t) {
        int n = t * 16 + c;
        be[t] = beff[n]; ga[t] = gamma[n]; bt[t] = beta[n];
    }

    // running per-column max (this lane's rows; cross-q reduce deferred)
    float pm[8];
    #pragma unroll
    for (int t = 0; t < 8; ++t) pm[t] = NEG_FILL;

    __syncthreads();

    // 8 iterations x (16 waves x 16 rows) = 2048 rows
    #pragma unroll 2
    for (int it = 0; it < 8; ++it) {
        const int row0 = it * 256 + wave * 16;     // this wave's 16-row strip
        const float* __restrict__ xrow = X + (base_row + row0 + c) * 128;

        // A-fragments: A[m=lane&15][k=q*8+j]
        bf16x8 afrag[4];
        #pragma unroll
        for (int kk = 0; kk < 4; ++kk) {
            float4 x0 = *(const float4*)(xrow + kk * 32 + q * 8);
            float4 x1 = *(const float4*)(xrow + kk * 32 + q * 8 + 4);
            afrag[kk] = pack8(x0, x1);
        }
        // mask for this lane's 4 output rows (16B-aligned int4)
        const int4 mk4 = *(const int4*)(mask + base_row + row0 + q * 4);

        f32x4 acc[8];
        const f32x4 zero = {0.f, 0.f, 0.f, 0.f};
        #pragma unroll
        for (int t = 0; t < 8; ++t) acc[t] = zero;

        #pragma unroll
        for (int kk = 0; kk < 4; ++kk) {
            #pragma unroll
            for (int t = 0; t < 8; ++t) {
                bf16x8 b = *(const bf16x8*)&Ws[t * 16 + c][kk * 32 + q * 8];
                acc[t] = __builtin_amdgcn_mfma_f32_16x16x32_bf16(afrag[kk], b, acc[t], 0, 0, 0);
            }
        }

        // C/D layout: col = lane&15, row = q*4 + r
        float v[8][4];
        #pragma unroll
        for (int t = 0; t < 8; ++t)
            #pragma unroll
            for (int r = 0; r < 4; ++r) v[t][r] = acc[t][r] + be[t];

        const int mks[4] = {mk4.x, mk4.y, mk4.z, mk4.w};
        #pragma unroll
        for (int r = 0; r < 4; ++r) {
            float s = 0.f, s2 = 0.f;
            #pragma unroll
            for (int t = 0; t < 8; ++t) { s += v[t][r]; s2 = fmaf(v[t][r], v[t][r], s2); }
            #pragma unroll
            for (int m = 1; m < 16; m <<= 1) {
                s  += __shfl_xor(s,  m, 64);
                s2 += __shfl_xor(s2, m, 64);
            }
            float mu  = s * (1.f / 128.f);
            float var = s2 * (1.f / 128.f) - mu * mu;
            float rs  = rsqrtf(var + 1e-3f);
            size_t rg = base_row + row0 + q * 4 + r;
            int mk = mks[r];
            #pragma unroll
            for (int t = 0; t < 8; ++t) {
                float y = fmaf((v[t][r] - mu) * rs, ga[t], bt[t]);
                y = fmaxf(y, 0.f);
                y = mk ? y : NEG_FILL;
                v[t][r] = y;
                __builtin_nontemporal_store(y, &out[rg * 256 + t * 16 + c]);
            }
        }

        // fold this strip's rows into the running per-lane max
        #pragma unroll
        for (int t = 0; t < 8; ++t) {
            float g0 = fmaxf(fmaxf(v[t][0], v[t][1]), fmaxf(v[t][2], v[t][3]));
            pm[t] = fmaxf(pm[t], g0);
        }
    }

    // block-level max-pool: values are >=0 or exactly -1e9 -> int cmp == float cmp
    #pragma unroll
    for (int t = 0; t < 8; ++t) {
        float p = pm[t];
        p = fmaxf(p, __shfl_xor(p, 16, 64));
        p = fmaxf(p, __shfl_xor(p, 32, 64));
        if (q == 0) atomicMax(&pool_s[t * 16 + c], __float_as_int(p));
    }
    __syncthreads();

    // stream this batch's broadcast half: 2048 rows x 32 float4 (1 MiB), NT
    const f32x4 pv = ((const f32x4*)pool_s)[tid & 31];
    f32x4* __restrict__ out4 = (f32x4*)out;
    #pragma unroll 8
    for (int i = 0; i < 64; ++i) {
        int idx = tid + i * 1024;          // 0..65535; idx&31 == tid&31
        size_t row = base_row + (idx >> 5);
        __builtin_nontemporal_store(pv, &out4[row * 64 + 32 + (idx & 31)]);
    }
}

extern "C" void kernel_launch(void* const* d_in, const int* in_sizes, int n_in,
                              void* d_out, int out_size, void* d_ws, size_t ws_size,
                              hipStream_t stream)
{
    const float* X     = (const float*)d_in[0];
    const int*   mask  = (const int*)d_in[1];
    const float* W1    = (const float*)d_in[2];
    const float* b1    = (const float*)d_in[3];
    const float* W2    = (const float*)d_in[4];
    const float* b2    = (const float*)d_in[5];
    const float* gamma = (const float*)d_in[6];
    const float* beta  = (const float*)d_in[7];
    float* out = (float*)d_out;

    short* WT   = (short*)d_ws;
    float* beff = (float*)((char*)d_ws + 32768);

    k_prep<<<65, 256, 0, stream>>>(W1, b1, W2, b2, WT, beff);
    k_main<<<256, 1024, 0, stream>>>(X, mask, WT, beff, gamma, beta, out);
}

// Round 7
// 748.043 us; speedup vs baseline: 1.1695x; 1.1695x over previous
//
#include <hip/hip_runtime.h>
#include <hip/hip_bf16.h>

#define NEG_FILL -1.0e9f

using bf16x8 = __attribute__((ext_vector_type(8))) short;
using f32x4  = __attribute__((ext_vector_type(4))) float;   // native clang vector

// round-to-nearest-even fp32 -> bf16 (no NaNs in this data)
static __device__ __forceinline__ short f2bf(float f) {
    union { float f; unsigned u; } a; a.f = f;
    unsigned r = a.u + 0x7FFFu + ((a.u >> 16) & 1u);
    return (short)(r >> 16);
}

// pack 8 floats -> bf16x8 via packed cvt (v_cvt_pk_bf16_f32)
static __device__ __forceinline__ bf16x8 pack8(float4 a, float4 b) {
    union { __hip_bfloat162 h[4]; bf16x8 v; } u;
    u.h[0] = __float22bfloat162_rn({a.x, a.y});
    u.h[1] = __float22bfloat162_rn({a.z, a.w});
    u.h[2] = __float22bfloat162_rn({b.x, b.y});
    u.h[3] = __float22bfloat162_rn({b.z, b.w});
    return u.v;
}

// ws layout:
// [0, 32768)        WT  bf16 [128][128]   WT[n][k] = (W1@W2)[k][n]
// [32768, 33280)    beff f32 [128]        b1@W2 + b2
// [33280, 164352)   pool f32-bits-as-int [256][128]

__global__ __launch_bounds__(256) void k_prep(
    const float* __restrict__ W1, const float* __restrict__ b1,
    const float* __restrict__ W2, const float* __restrict__ b2,
    short* __restrict__ WT, float* __restrict__ beff, int* __restrict__ pool)
{
    int blk = blockIdx.x, tid = threadIdx.x;
    if (blk < 128) {                      // pool init: 128*256 = 32768 entries
        pool[blk * 256 + tid] = __float_as_int(NEG_FILL);
        return;
    }
    if (blk < 192) {                      // Weff^T: 64 blocks * 256 = 16384 entries
        int e = (blk - 128) * 256 + tid;  // e = n*128 + k
        int n = e >> 7, k = e & 127;
        float s = 0.f;
        #pragma unroll 8
        for (int h = 0; h < 64; ++h) s = fmaf(W1[k * 64 + h], W2[h * 128 + n], s);
        WT[e] = f2bf(s);
    } else if (tid < 128) {               // beff
        float s = b2[tid];
        for (int h = 0; h < 64; ++h) s = fmaf(b1[h], W2[h * 128 + tid], s);
        beff[tid] = s;
    }
}

// Main fused kernel, R5 geometry (4096 blocks x 512 thr, wave = 16 rows) with
// TRANSPOSED MFMA OUTPUT. R6 counters showed hbm_bytes 1.37GB vs 804MB ideal:
// the scattered scalar C-stores cause partial-line write amplification, and
// the column-strip lane layout forces 32 scalar stores + 16 shuffle rounds
// per lane. Fix: swap mfma operand order -- mfma(Wfrag, Xfrag) computes
// D = W^T X^T = out^T. Fragment LOADS are identical (A and B frags share the
// same row=lane&15, k=(lane>>4)*8+j pattern); only the lane->element map of D
// changes: each lane now owns ONE output row (row = lane&15), cols
// t*16+q*4+{0..3}. Gains: 8 aligned float4 stores (plain, so L2 merges full
// lines), float4 beff/gamma/beta loads, LN reduce = 2 shfl_xor rounds (q
// lanes only), scalar mask load.
__global__ __launch_bounds__(512) void k_main(
    const float* __restrict__ X, const int* __restrict__ mask,
    const short* __restrict__ WT, const float* __restrict__ beff,
    const float* __restrict__ gamma, const float* __restrict__ beta,
    float* __restrict__ out, int* __restrict__ pool)
{
    __shared__ short Ws[128][136];   // +8 shorts pad
    __shared__ int pool_s[128];

    const int tid = threadIdx.x;
    const int rowbase = blockIdx.x * 128;  // 128 rows, within one b (2048%128==0)

    if (tid < 128) pool_s[tid] = __float_as_int(NEG_FILL);

    // stage Weff^T (bf16) into LDS: 2048 x 16B over 512 threads
    #pragma unroll
    for (int i = 0; i < 4; ++i) {
        int g = tid + i * 512;             // short8 id
        int n = g >> 4, koff = (g & 15) * 8;
        *(bf16x8*)&Ws[n][koff] = *(const bf16x8*)(WT + g * 8);
    }

    const int wave = tid >> 6, lane = tid & 63;
    const int c = lane & 15, q = lane >> 4;
    const int rowg = rowbase + wave * 16 + c;      // this lane's output row
    const float* __restrict__ xrow = X + (size_t)rowg * 128;

    // hoisted: X fragments (B-operand now, same bytes as before) + mask
    bf16x8 xfrag[4];
    #pragma unroll
    for (int kk = 0; kk < 4; ++kk) {
        float4 x0 = *(const float4*)(xrow + kk * 32 + q * 8);
        float4 x1 = *(const float4*)(xrow + kk * 32 + q * 8 + 4);
        xfrag[kk] = pack8(x0, x1);
    }
    const int mk = mask[rowg];             // one row per lane -> scalar mask

    __syncthreads();

    f32x4 acc[8];
    const f32x4 zero = {0.f, 0.f, 0.f, 0.f};
    #pragma unroll
    for (int t = 0; t < 8; ++t) acc[t] = zero;

    // D = Weff^T (A) x X^T (B): A-frag read == old B-frag read, B-frag == old
    // A-frag. acc[t] reg r = out[row=c][col=t*16+q*4+r].
    #pragma unroll
    for (int kk = 0; kk < 4; ++kk) {
        #pragma unroll
        for (int t = 0; t < 8; ++t) {
            bf16x8 w = *(const bf16x8*)&Ws[t * 16 + c][kk * 32 + q * 8];
            acc[t] = __builtin_amdgcn_mfma_f32_16x16x32_bf16(w, xfrag[kk], acc[t], 0, 0, 0);
        }
    }

    // epilogue: +beff, LN stats over this lane's 32 cols + 4 q-lanes
    float v[8][4];
    float s = 0.f, s2 = 0.f;
    #pragma unroll
    for (int t = 0; t < 8; ++t) {
        float4 be4 = *(const float4*)(beff + t * 16 + q * 4);
        v[t][0] = acc[t][0] + be4.x;
        v[t][1] = acc[t][1] + be4.y;
        v[t][2] = acc[t][2] + be4.z;
        v[t][3] = acc[t][3] + be4.w;
        #pragma unroll
        for (int r = 0; r < 4; ++r) { s += v[t][r]; s2 = fmaf(v[t][r], v[t][r], s2); }
    }
    s  += __shfl_xor(s, 16, 64);  s  += __shfl_xor(s, 32, 64);
    s2 += __shfl_xor(s2, 16, 64); s2 += __shfl_xor(s2, 32, 64);
    float mu  = s * (1.f / 128.f);
    float var = s2 * (1.f / 128.f) - mu * mu;
    float rs  = rsqrtf(var + 1e-3f);

    // LN + ReLU + mask-fill; aligned float4 stores (plain: L2 merges lines)
    float4* __restrict__ orow = (float4*)(out + (size_t)rowg * 256);
    #pragma unroll
    for (int t = 0; t < 8; ++t) {
        float4 ga4 = *(const float4*)(gamma + t * 16 + q * 4);
        float4 bt4 = *(const float4*)(beta  + t * 16 + q * 4);
        float4 yv;
        float y0 = fmaxf(fmaf((v[t][0] - mu) * rs, ga4.x, bt4.x), 0.f);
        float y1 = fmaxf(fmaf((v[t][1] - mu) * rs, ga4.y, bt4.y), 0.f);
        float y2 = fmaxf(fmaf((v[t][2] - mu) * rs, ga4.z, bt4.z), 0.f);
        float y3 = fmaxf(fmaf((v[t][3] - mu) * rs, ga4.w, bt4.w), 0.f);
        yv.x = mk ? y0 : NEG_FILL;  v[t][0] = yv.x;
        yv.y = mk ? y1 : NEG_FILL;  v[t][1] = yv.y;
        yv.z = mk ? y2 : NEG_FILL;  v[t][2] = yv.z;
        yv.w = mk ? y3 : NEG_FILL;  v[t][3] = yv.w;
        orow[t * 4 + q] = yv;
    }

    // max-pool over the wave's 16 rows: reduce across the 16 c-lanes
    #pragma unroll
    for (int t = 0; t < 8; ++t)
        #pragma unroll
        for (int r = 0; r < 4; ++r) {
            float p = v[t][r];
            p = fmaxf(p, __shfl_xor(p, 1, 64));
            p = fmaxf(p, __shfl_xor(p, 2, 64));
            p = fmaxf(p, __shfl_xor(p, 4, 64));
            p = fmaxf(p, __shfl_xor(p, 8, 64));
            v[t][r] = p;                   // all c-lanes now hold the col max
        }
    // spread the 32 LDS atomics over lanes c=0..7 (t = c), conflict-free banks
    if (c < 8) {
        int t = c;
        #pragma unroll
        for (int r = 0; r < 4; ++r)
            atomicMax(&pool_s[t * 16 + q * 4 + r], __float_as_int(v[t][r]));
    }
    __syncthreads();
    if (tid < 128) {
        int b = rowbase >> 11;             // 2048 rows per batch
        atomicMax(&pool[b * 128 + tid], pool_s[tid]);
    }
}

// broadcast pooled vector into out[:, :, 128:256]
// grid-stride: 4096 blocks x 256 thr x 16 float4 = 16.7M float4 (256 MiB)
__global__ __launch_bounds__(256) void k_bcast(
    const f32x4* __restrict__ pool4, f32x4* __restrict__ out4)
{
    unsigned base = blockIdx.x * 256 + threadIdx.x;
    #pragma unroll
    for (int i = 0; i < 16; ++i) {
        unsigned idx = base + (unsigned)i * (4096u * 256u);
        unsigned row = idx >> 5;        // 32 float4 per row-half
        unsigned c4  = idx & 31;
        unsigned b   = row >> 11;
        f32x4 pv = pool4[b * 32 + c4];
        __builtin_nontemporal_store(pv, &out4[(size_t)row * 64 + 32 + c4]);
    }
}

extern "C" void kernel_launch(void* const* d_in, const int* in_sizes, int n_in,
                              void* d_out, int out_size, void* d_ws, size_t ws_size,
                              hipStream_t stream)
{
    const float* X     = (const float*)d_in[0];
    const int*   mask  = (const int*)d_in[1];
    const float* W1    = (const float*)d_in[2];
    const float* b1    = (const float*)d_in[3];
    const float* W2    = (const float*)d_in[4];
    const float* b2    = (const float*)d_in[5];
    const float* gamma = (const float*)d_in[6];
    const float* beta  = (const float*)d_in[7];
    float* out = (float*)d_out;

    short* WT   = (short*)d_ws;
    float* beff = (float*)((char*)d_ws + 32768);
    int*   pool = (int*)((char*)d_ws + 33280);

    k_prep<<<193, 256, 0, stream>>>(W1, b1, W2, b2, WT, beff, pool);
    k_main<<<4096, 512, 0, stream>>>(X, mask, WT, beff, gamma, beta, out, pool);
    k_bcast<<<4096, 256, 0, stream>>>((const f32x4*)pool, (f32x4*)out);
}